// Round 7
// baseline (14697.058 us; speedup 1.0000x reference)
//
#include <hip/hip_runtime.h>
#include <math.h>

#define TSTEPS 4096
#define DIM 1024
#define GDIM 4096
#define ENC_NB 64
#define NSEG 64
#define SEGLEN 64

typedef short bf16x8 __attribute__((ext_vector_type(8)));
typedef float f32x4 __attribute__((ext_vector_type(4)));
typedef unsigned int uint4v __attribute__((ext_vector_type(4)));

__device__ __forceinline__ float sigmoidf_(float x) {
    return 1.0f / (1.0f + expf(-x));
}

// Load 8 consecutive fp32, split each into bf16 hi (truncate) + bf16 lo
// (truncated residual). x ~= hi + lo to ~2^-15 relative.
__device__ __forceinline__ void loadcvt(const float* __restrict__ p,
                                        bf16x8& hi, bf16x8& lo)
{
    float4 a = *(const float4*)p;
    float4 b = *(const float4*)(p + 4);
    float f[8] = {a.x, a.y, a.z, a.w, b.x, b.y, b.z, b.w};
    uint4v hw, lw;
    #pragma unroll
    for (int j = 0; j < 4; ++j) {
        unsigned u0 = __float_as_uint(f[2*j]);
        unsigned u1 = __float_as_uint(f[2*j+1]);
        unsigned m0 = u0 & 0xffff0000u;
        unsigned m1 = u1 & 0xffff0000u;
        float r0 = f[2*j]   - __uint_as_float(m0);
        float r1 = f[2*j+1] - __uint_as_float(m1);
        hw[j] = __builtin_amdgcn_perm(u1, u0, 0x07060302u);
        lw[j] = __builtin_amdgcn_perm(__float_as_uint(r1), __float_as_uint(r0),
                                      0x07060302u);
    }
    hi = __builtin_bit_cast(bf16x8, hw);
    lo = __builtin_bit_cast(bf16x8, lw);
}

// C[M,N] = A1[M,K]·B1[N,K]^T (+ A2·B2^T if DUAL) + bias1 + bias2
template<bool DUAL>
__global__ __launch_bounds__(256)
void gemm_split(const float* __restrict__ A1, const float* __restrict__ B1,
                const float* __restrict__ A2, const float* __restrict__ B2,
                const float* __restrict__ bias1, const float* __restrict__ bias2,
                float* __restrict__ C, int N)
{
    const int lane = threadIdx.x & 63;
    const int wid  = threadIdx.x >> 6;
    const int m0 = blockIdx.y * 128 + (wid >> 1) * 64;
    const int n0 = blockIdx.x * 128 + (wid & 1) * 64;
    const int rA   = m0 + (lane & 15);
    const int cB   = n0 + (lane & 15);
    const int koff = (lane >> 4) * 8;

    f32x4 acc[4][4] = {};

    const int npass = DUAL ? 2 : 1;
    for (int pass = 0; pass < npass; ++pass) {
        const float* __restrict__ A = (DUAL && pass) ? A2 : A1;
        const float* __restrict__ B = (DUAL && pass) ? B2 : B1;
        for (int k0 = 0; k0 < 1024; k0 += 32) {
            bf16x8 ah[4], al[4], bh[4], bl[4];
            #pragma unroll
            for (int i = 0; i < 4; ++i)
                loadcvt(A + (size_t)(rA + i * 16) * 1024 + k0 + koff, ah[i], al[i]);
            #pragma unroll
            for (int j = 0; j < 4; ++j)
                loadcvt(B + (size_t)(cB + j * 16) * 1024 + k0 + koff, bh[j], bl[j]);
            #pragma unroll
            for (int i = 0; i < 4; ++i)
                #pragma unroll
                for (int j = 0; j < 4; ++j) {
                    acc[i][j] = __builtin_amdgcn_mfma_f32_16x16x32_bf16(
                        ah[i], bh[j], acc[i][j], 0, 0, 0);
                    acc[i][j] = __builtin_amdgcn_mfma_f32_16x16x32_bf16(
                        ah[i], bl[j], acc[i][j], 0, 0, 0);
                    acc[i][j] = __builtin_amdgcn_mfma_f32_16x16x32_bf16(
                        al[i], bh[j], acc[i][j], 0, 0, 0);
                }
        }
    }

    const int er = (lane >> 4) * 4;
    const int ec = lane & 15;
    #pragma unroll
    for (int j = 0; j < 4; ++j) {
        int col = n0 + j * 16 + ec;
        float bb = bias1[col] + bias2[col];
        #pragma unroll
        for (int i = 0; i < 4; ++i) {
            int rowb = m0 + i * 16 + er;
            #pragma unroll
            for (int r = 0; r < 4; ++r)
                C[(size_t)(rowb + r) * N + col] = acc[i][j][r] + bb;
        }
    }
}

// ---------------- Encoder sequential scan, gate-fused threads.
// 64 blocks x 256 threads (4 waves), ~300 VGPR. Thread (hi = t>>4, sub = t&15)
// owns ALL 4 gate rows of channel hbase+hi for k-chunk sub: 4x16 float4 of
// Whh in registers. Per step it reads its 256B h-chunk from LDS ONCE and
// produces 4 partial dots -> 4x less LDS traffic than one-row-per-thread.
// Exchange: fused tag|payload 8B slots (each thread polls its 4), throttled
// by s_sleep; publish batched+coalesced by wave 0 after a 4-wave barrier.
__global__ __launch_bounds__(256, 1)
void encoder_scan(const float* __restrict__ Xg,   // [4096][4096]
                  const float* __restrict__ Whh,  // [4096][1024]
                  float* __restrict__ signal,     // [4097][1024]
                  unsigned long long* __restrict__ slots, // [2][1024] zeroed
                  float* __restrict__ l1_acc)
{
    const int b = blockIdx.x;
    const int t = threadIdx.x;          // 0..255
    const int hbase = b * 16;
    const int hi = t >> 4;              // channel 0..15
    const int sub = t & 15;             // k-chunk 0..15 (64 floats each)
    const int ch = hbase + hi;

    // weights: 4 gates x 16 float4 = 256 VGPR
    float4 wreg[4][16];
    #pragma unroll
    for (int q = 0; q < 4; ++q) {
        const float4* wrow =
            (const float4*)(Whh + (size_t)(q * 1024 + ch) * 1024 + sub * 64);
        #pragma unroll
        for (int i = 0; i < 16; ++i) wreg[q][i] = wrow[i];
    }

    __shared__ float hls[16 * 68];      // chunk-major, stride 68 (2-way max)
    __shared__ float hstage[16];

    float c = 0.f;    // cell state: lives in sub==0 lane of each 16-lane group
    float l1 = 0.f;   // t<16 only

    for (int step = 0; step < TSTEPS; ++step) {
        const unsigned us = (unsigned)step;

        // prefetch the 4 gate pre-act inputs for this channel (hides in poll)
        float xg0 = 0.f, xg1 = 0.f, xg2 = 0.f, xg3 = 0.f;
        if (sub == 0) {
            const float* xr = Xg + (size_t)step * GDIM + ch;
            xg0 = xr[0]; xg1 = xr[1024]; xg2 = xr[2048]; xg3 = xr[3072];
        }

        // poll own 4 slots (h indices 4t..4t+3); tag rides with payload
        const unsigned long long* sp = slots + (size_t)(step & 1) * 1024 + 4 * t;
        unsigned long long v0, v1, v2, v3;
        while (true) {
            v0 = __hip_atomic_load(sp + 0, __ATOMIC_RELAXED, __HIP_MEMORY_SCOPE_AGENT);
            v1 = __hip_atomic_load(sp + 1, __ATOMIC_RELAXED, __HIP_MEMORY_SCOPE_AGENT);
            v2 = __hip_atomic_load(sp + 2, __ATOMIC_RELAXED, __HIP_MEMORY_SCOPE_AGENT);
            v3 = __hip_atomic_load(sp + 3, __ATOMIC_RELAXED, __HIP_MEMORY_SCOPE_AGENT);
            unsigned tmin = min(min((unsigned)(v0 >> 32), (unsigned)(v1 >> 32)),
                                min((unsigned)(v2 >> 32), (unsigned)(v3 >> 32)));
            if (tmin >= us) break;
            __builtin_amdgcn_s_sleep(1);
        }
        // h indices 4t..4t+3 live in chunk (t>>4), offset 4*(t&15)
        *(float4*)(hls + hi * 68 + 4 * sub) =
            make_float4(__uint_as_float((unsigned)v0), __uint_as_float((unsigned)v1),
                        __uint_as_float((unsigned)v2), __uint_as_float((unsigned)v3));
        __syncthreads();                                   // barrier A (4 waves)

        // dot: one 256B h-chunk read, reused across the 4 gates
        float a0 = 0.f, a1 = 0.f, a2 = 0.f, a3 = 0.f;
        const float* hv = hls + sub * 68;
        #pragma unroll
        for (int i = 0; i < 16; ++i) {
            float4 h4 = *(const float4*)(hv + i * 4);
            a0 = fmaf(wreg[0][i].x, h4.x, a0); a0 = fmaf(wreg[0][i].y, h4.y, a0);
            a0 = fmaf(wreg[0][i].z, h4.z, a0); a0 = fmaf(wreg[0][i].w, h4.w, a0);
            a1 = fmaf(wreg[1][i].x, h4.x, a1); a1 = fmaf(wreg[1][i].y, h4.y, a1);
            a1 = fmaf(wreg[1][i].z, h4.z, a1); a1 = fmaf(wreg[1][i].w, h4.w, a1);
            a2 = fmaf(wreg[2][i].x, h4.x, a2); a2 = fmaf(wreg[2][i].y, h4.y, a2);
            a2 = fmaf(wreg[2][i].z, h4.z, a2); a2 = fmaf(wreg[2][i].w, h4.w, a2);
            a3 = fmaf(wreg[3][i].x, h4.x, a3); a3 = fmaf(wreg[3][i].y, h4.y, a3);
            a3 = fmaf(wreg[3][i].z, h4.z, a3); a3 = fmaf(wreg[3][i].w, h4.w, a3);
        }
        // butterfly over the 16 chunk-lanes (stays within the 16-lane group)
        #pragma unroll
        for (int m = 1; m <= 8; m <<= 1) {
            a0 += __shfl_xor(a0, m);
            a1 += __shfl_xor(a1, m);
            a2 += __shfl_xor(a2, m);
            a3 += __shfl_xor(a3, m);
        }

        if (sub == 0) {   // 16 parallel channel-lanes
            float iv = sigmoidf_(a0 + xg0);
            float fv = sigmoidf_(a1 + xg1);
            float gv = tanhf(a2 + xg2);
            float ov = sigmoidf_(a3 + xg3);
            c = fmaf(fv, c, iv * gv);
            hstage[hi] = ov * tanhf(c);
        }
        __syncthreads();                                   // barrier B

        // batched publish: wave 0, coalesced 128B slot store + 64B signal
        if (t < 16) {
            float h = hstage[t];
            unsigned long long pv =
                ((unsigned long long)(us + 1) << 32) | __float_as_uint(h);
            __hip_atomic_store(slots + (size_t)((step + 1) & 1) * 1024 + hbase + t,
                               pv, __ATOMIC_RELAXED, __HIP_MEMORY_SCOPE_AGENT);
            signal[(size_t)step * DIM + hbase + t] = h;
            l1 += fabsf(h);
        }
    }
    if (t < 16) {
        #pragma unroll
        for (int off = 8; off >= 1; off >>= 1) l1 += __shfl_xor(l1, off);
        if (t == 0) atomicAdd(l1_acc, l1);
    }
}

// ---------------- Decoder: segmented affine scan. c_t = f_t*c + (i_t*g_t).
__global__ __launch_bounds__(256)
void dec_compose(const float* __restrict__ G, float* __restrict__ Aseg,
                 float* __restrict__ Bseg)
{
    const int j = blockIdx.x * 256 + threadIdx.x;
    const int s = blockIdx.y;
    const int t0 = s * SEGLEN;
    const int t1 = min(t0 + SEGLEN, TSTEPS - 1);
    float A = 1.f, Bv = 0.f;
    for (int t = t0; t < t1; ++t) {
        const float* g = G + (size_t)t * GDIM;
        float iv = sigmoidf_(g[j]);
        float fv = sigmoidf_(g[j + 1024]);
        float gv = tanhf(g[j + 2048]);
        A *= fv;
        Bv = fmaf(fv, Bv, iv * gv);
    }
    Aseg[s * DIM + j] = A;
    Bseg[s * DIM + j] = Bv;
}

__global__ __launch_bounds__(1024)
void dec_scan(const float* __restrict__ Aseg, const float* __restrict__ Bseg,
              float* __restrict__ cinit)
{
    const int j = threadIdx.x;
    float c = 0.f;
    for (int s = 0; s < NSEG; ++s) {
        cinit[s * DIM + j] = c;
        c = fmaf(Aseg[s * DIM + j], c, Bseg[s * DIM + j]);
    }
}

__global__ __launch_bounds__(256)
void dec_emit(const float* __restrict__ G, const float* __restrict__ inp,
              const float* __restrict__ cinit, float* __restrict__ mse_acc)
{
    const int j = blockIdx.x * 256 + threadIdx.x;
    const int s = blockIdx.y;
    const int t0 = s * SEGLEN;
    const int t1 = min(t0 + SEGLEN, TSTEPS - 1);
    float c = cinit[s * DIM + j];
    float acc = 0.f;
    for (int t = t0; t < t1; ++t) {
        const float* g = G + (size_t)t * GDIM;
        float iv = sigmoidf_(g[j]);
        float fv = sigmoidf_(g[j + 1024]);
        float gv = tanhf(g[j + 2048]);
        float ov = sigmoidf_(g[j + 3072]);
        c = fmaf(fv, c, iv * gv);
        float d = ov * tanhf(c);
        float diff = d - inp[(size_t)(t + 1) * DIM + j];
        acc = fmaf(diff, diff, acc);
    }
    #pragma unroll
    for (int off = 32; off >= 1; off >>= 1) acc += __shfl_xor(acc, off);
    if ((threadIdx.x & 63) == 0) atomicAdd(mse_acc, acc);
}

__global__ void finalize(const float* __restrict__ scal, float* __restrict__ out)
{
    float mse = scal[0] / ((float)(TSTEPS - 1) * (float)DIM);
    float l1  = scal[1] / ((float)TSTEPS * (float)DIM);
    out[0] = mse + 0.25f * l1;
    out[1] = mse;
    out[2] = l1;
}

extern "C" void kernel_launch(void* const* d_in, const int* in_sizes, int n_in,
                              void* d_out, int out_size, void* d_ws, size_t ws_size,
                              hipStream_t stream)
{
    const float* inputs  = (const float*)d_in[0];
    const float* enc_Wih = (const float*)d_in[1];
    const float* enc_Whh = (const float*)d_in[2];
    const float* enc_bih = (const float*)d_in[3];
    const float* enc_bhh = (const float*)d_in[4];
    const float* dec_Wih = (const float*)d_in[5];
    const float* dec_Whh = (const float*)d_in[6];
    const float* dec_bih = (const float*)d_in[7];
    const float* dec_bhh = (const float*)d_in[8];
    float* out = (float*)d_out;

    float* ws = (float*)d_ws;
    float* gates  = ws;                            // [4096][4096] Xenc then Gdec
    float* signal = ws + (size_t)16777216;         // [4097][1024] (row 4096 zero)
    unsigned long long* slots =
        (unsigned long long*)(ws + (size_t)20972544);   // [2][1024] u64
    float* scal   = ws + (size_t)20976640;         // [mse, l1] + pad
    float* Aseg   = ws + (size_t)20976648;         // [64][1024]
    float* Bseg   = ws + (size_t)21042184;         // [64][1024]
    float* cinit  = ws + (size_t)21107720;         // [64][1024]
    float* mse_acc = scal + 0;
    float* l1_acc  = scal + 1;

    // one memset: signal row 4096 (1024 f) + slots (4096 f) + scal (8 f)
    hipMemsetAsync(ws + (size_t)20971520, 0, (size_t)(1024 + 4096 + 8) * 4, stream);

    dim3 b256(256);
    // Xenc = inputs @ enc_Wih^T + enc_bih + enc_bhh   (split-bf16 MFMA)
    gemm_split<false><<<dim3(32, 32), b256, 0, stream>>>(
        inputs, enc_Wih, nullptr, nullptr, enc_bih, enc_bhh, gates, GDIM);
    // sequential encoder (fuses L1 accumulation)
    encoder_scan<<<dim3(ENC_NB), b256, 0, stream>>>(
        gates, enc_Whh, signal, slots, l1_acc);
    // Gdec = signal[1:] @ dec_Wih^T + inputs @ dec_Whh^T + dec biases (fused)
    gemm_split<true><<<dim3(32, 32), b256, 0, stream>>>(
        signal + DIM, dec_Wih, inputs, dec_Whh, dec_bih, dec_bhh, gates, GDIM);
    // decoder segmented scan + mse
    dec_compose<<<dim3(4, NSEG), b256, 0, stream>>>(gates, Aseg, Bseg);
    dec_scan<<<dim3(1), dim3(1024), 0, stream>>>(Aseg, Bseg, cinit);
    dec_emit<<<dim3(4, NSEG), b256, 0, stream>>>(gates, inputs, cinit, mse_acc);
    finalize<<<dim3(1), dim3(1), 0, stream>>>(scal, out);
}